// Round 4
// baseline (4108.789 us; speedup 1.0000x reference)
//
#include <hip/hip_runtime.h>

// RNNModule: LSTM-like scan with shared gate pre-activation.
// B=128, L=256, D=512, H=1024, O=2.
//
//  k0_prep : transpose+convert Wh/Wx to bf16 col-major, bxh=bx+bh,
//            poison-fill hs (0xAA sentinel for k2's dataflow).
//  k1_xproj: xp[l][b][n] = bf16( x[b,l,:]@Wx[:,n] + bx[n] + bh[n] )  (MFMA,
//            operands swapped so the C-layout is column-contiguous per lane).
//  k2_scan : 256 steps, pure dataflow, no barriers. 8 groups (16 batch rows)
//            x 32 WGs (32 cols each; wave owns 16). Wh slice register-resident.
//            Computes z^T = Wh^T · h^T (operand swap) so each lane's 4 results
//            are 4 consecutive h-columns -> ONE atomic 8B agent store (updates
//            local L2 via write-through AND L3). Consumers poll with sc0 loads
//            (bypass L1, hit the XCD-local L2 -- fast path under blk&7
//            round-robin placement) and escalate to agent-scope loads after 16
//            retries (L3 truth -> correct under ANY WG->XCD mapping, G16).
//  k3_out  : out[b*L+l] = mask ? sigmoid(hs[l][b]@Wo + bo) : (0,1)

#define B_ 128
#define L_ 256
#define D_ 512
#define H_ 1024

#define POISON64 0xAAAAAAAAAAAAAAAAull

typedef __attribute__((ext_vector_type(8))) short short8;
typedef __attribute__((ext_vector_type(4))) float f32x4;
typedef __attribute__((ext_vector_type(2))) float f32x2;
typedef __attribute__((ext_vector_type(4))) unsigned short u16x4;
typedef __attribute__((ext_vector_type(4))) int i32x4;

__device__ __forceinline__ unsigned short f2bf(float f) {
    unsigned int u = __float_as_uint(f);
    return (unsigned short)((u + 0x8000u) >> 16);  // round-half-up to bf16
}
__device__ __forceinline__ float bf2f(unsigned short s) {
    return __uint_as_float(((unsigned int)s) << 16);
}

// agent-scope (coherence-point) 8B atomic load/store
__device__ __forceinline__ unsigned long long ld8(const unsigned short* p) {
    return __hip_atomic_load((const unsigned long long*)p,
                             __ATOMIC_RELAXED, __HIP_MEMORY_SCOPE_AGENT);
}
__device__ __forceinline__ void st8(unsigned short* p, unsigned long long v) {
    __hip_atomic_store((unsigned long long*)p, v,
                       __ATOMIC_RELAXED, __HIP_MEMORY_SCOPE_AGENT);
}

// 16B load, sc0: bypass L1 (never serve stale lines on poll retry), may hit
// the XCD-local L2. Immediate-offset variant for the burst, pointer variant
// for the (rare) retry path.
template<int OFF>
__device__ __forceinline__ i32x4 ld16_sc0(const unsigned short* p) {
    i32x4 r;
    asm volatile("global_load_dwordx4 %0, %1, off offset:%2 sc0"
                 : "=v"(r) : "v"(p), "i"(OFF) : "memory");
    return r;
}
__device__ __forceinline__ i32x4 ld16_sc0p(const unsigned short* p) {
    i32x4 r;
    asm volatile("global_load_dwordx4 %0, %1, off sc0"
                 : "=v"(r) : "v"(p) : "memory");
    return r;
}
// drain vmcnt and pin the 4 tied fragments so no use is scheduled earlier
__device__ __forceinline__ void wait_vm0(i32x4& a, i32x4& b, i32x4& c, i32x4& d) {
    asm volatile("s_waitcnt vmcnt(0)" : "+v"(a), "+v"(b), "+v"(c), "+v"(d));
}
// fragment still (partially) poison? producer stores are atomic 8B chunks,
// canonicalized, so checking each 8B half against the full pattern suffices.
__device__ __forceinline__ bool pois(const i32x4 v) {
    bool h0 = (v.x == (int)0xAAAAAAAAu) && (v.y == (int)0xAAAAAAAAu);
    bool h1 = (v.z == (int)0xAAAAAAAAu) && (v.w == (int)0xAAAAAAAAu);
    return h0 | h1;
}

// ---------------------------------------------------------------- k0: prep
__global__ __launch_bounds__(256) void k0_prep(
    const float* __restrict__ Wh, const float* __restrict__ Wx,
    const float* __restrict__ bh, const float* __restrict__ bx,
    unsigned short* __restrict__ Whb_t, unsigned short* __restrict__ Wxb_t,
    float* __restrict__ bxh, unsigned short* __restrict__ hs)
{
    const int stride = gridDim.x * blockDim.x;
    const int t0 = blockIdx.x * blockDim.x + threadIdx.x;
    for (int i = t0; i < H_ * H_; i += stride) {
        int n = i >> 10, k = i & 1023;
        Whb_t[i] = f2bf(Wh[k * H_ + n]);
    }
    for (int i = t0; i < H_ * D_; i += stride) {
        int n = i >> 9, k = i & 511;
        Wxb_t[i] = f2bf(Wx[k * H_ + n]);
    }
    for (int i = t0; i < H_; i += stride) bxh[i] = bx[i] + bh[i];
    // poison-fill hs: k2's sentinel must not depend on harness pre-state
    unsigned long long* hp = (unsigned long long*)hs;
    const int nq = (L_ * B_ * H_) / 4;
    for (int i = t0; i < nq; i += stride) hp[i] = POISON64;
}

// ------------------------------------------------------------ k1: x @ Wx
// Operand-swapped MFMA (A=Wx^T frag, B=x frag): D[row=outcol][col=batch],
// so each lane's 4 results are 4 consecutive n -> 8B store into xp[l][b][n].
__global__ __launch_bounds__(256) void k1_xproj(
    const float* __restrict__ x, const unsigned short* __restrict__ Wxb_t,
    const float* __restrict__ bxh, unsigned short* __restrict__ xp)
{
    const int nt   = blockIdx.x & 3;
    const int mt   = blockIdx.x >> 2;
    const int w    = threadIdx.x >> 6;
    const int lane = threadIdx.x & 63;
    const int m    = lane & 15, q = lane >> 4;
    const int m0   = mt * 64;
    const int l    = m0 >> 7;
    const int brow = (m0 & 127) + w * 16;
    const int n0   = nt * 256;

    const float* ap = x + ((size_t)(brow + m) * L_ + l) * D_ + q * 8;

    f32x4 acc[16];
#pragma unroll
    for (int t = 0; t < 16; ++t) acc[t] = (f32x4){0.f, 0.f, 0.f, 0.f};

#pragma unroll 4
    for (int kk = 0; kk < 16; ++kk) {
        f32x4 av0 = *(const f32x4*)(ap + kk * 32);
        f32x4 av1 = *(const f32x4*)(ap + kk * 32 + 4);
        short8 a8;
        a8[0] = (short)f2bf(av0[0]); a8[1] = (short)f2bf(av0[1]);
        a8[2] = (short)f2bf(av0[2]); a8[3] = (short)f2bf(av0[3]);
        a8[4] = (short)f2bf(av1[0]); a8[5] = (short)f2bf(av1[1]);
        a8[6] = (short)f2bf(av1[2]); a8[7] = (short)f2bf(av1[3]);
#pragma unroll
        for (int t = 0; t < 16; ++t) {
            short8 b8 = *(const short8*)(Wxb_t +
                        (size_t)(n0 + t * 16 + m) * D_ + kk * 32 + q * 8);
            acc[t] = __builtin_amdgcn_mfma_f32_16x16x32_bf16(b8, a8, acc[t], 0, 0, 0);
        }
    }

#pragma unroll
    for (int t = 0; t < 16; ++t) {
        const int c0 = n0 + t * 16 + q * 4;       // 4 consecutive out-cols
        f32x4 bias = *(const f32x4*)(bxh + c0);
        u16x4 o;
#pragma unroll
        for (int r = 0; r < 4; ++r) o[r] = f2bf(acc[t][r] + bias[r]);
        *(u16x4*)(xp + ((size_t)l * B_ + brow + m) * H_ + c0) = o;
    }
}

// ------------------------------------------------------------- k2: scan
// Grid: 256 WGs x 128 thr. group g=blk&7 (batch rows g*16..+15; with
// round-robin dispatch the whole group shares one XCD -> L2-local exchange),
// wgi=blk>>3 (cols wgi*32..+31; wave w owns 16). No barriers, no LDS.
__global__ __launch_bounds__(128, 1) void k2_scan(
    const unsigned short* __restrict__ Whb_t,
    const unsigned short* __restrict__ xp,
    unsigned short* __restrict__ hs)
{
    const int g    = blockIdx.x & 7;
    const int wgi  = blockIdx.x >> 3;
    const int tid  = threadIdx.x;
    const int w    = tid >> 6;
    const int lane = tid & 63;
    const int m    = lane & 15, q = lane >> 4;
    const int b0   = g * 16;
    const int colbase = wgi * 32 + w * 16;

    // persistent A fragments: Wh^T[colbase+m][k], k = kk*32 + q*8 + j
    short8 bfrag[32];
    {
        const unsigned short* wp = Whb_t + (size_t)(colbase + m) * H_ + q * 8;
#pragma unroll
        for (int kk = 0; kk < 32; ++kk)
            bfrag[kk] = *(const short8*)(wp + kk * 32);
    }

    float c[4] = {0.f, 0.f, 0.f, 0.f};

    for (int l = 0; l < L_; ++l) {
        // xp addend for (batch b0+m, cols colbase+q*4..+3): independent of
        // the recurrence, issue early
        u16x4 xv = *(const u16x4*)(xp + ((size_t)l * B_ + b0 + m) * H_ + colbase + q * 4);

        f32x4 acc0 = {0.f,0.f,0.f,0.f}, acc1 = {0.f,0.f,0.f,0.f};
        f32x4 acc2 = {0.f,0.f,0.f,0.f}, acc3 = {0.f,0.f,0.f,0.f};
        if (l > 0) {
            // B fragments: h[l-1][b0+m][k], k = j*32 + q*8 .. +7  (16B each)
            const unsigned short* ap =
                hs + ((size_t)(l - 1) * B_ + b0 + m) * H_ + q * 8;
            i32x4 f[32];
            // burst-issue all 32 loads (sc0, stay in flight together)
#define LDQ(J) \
            f[4*(J)+0] = ld16_sc0<256*(J)+  0>(ap); \
            f[4*(J)+1] = ld16_sc0<256*(J)+ 64>(ap); \
            f[4*(J)+2] = ld16_sc0<256*(J)+128>(ap); \
            f[4*(J)+3] = ld16_sc0<256*(J)+192>(ap);
            LDQ(0) LDQ(1) LDQ(2) LDQ(3) LDQ(4) LDQ(5) LDQ(6) LDQ(7)
#undef LDQ
#pragma unroll
            for (int jq = 0; jq < 8; ++jq) {
                i32x4 F0 = f[4*jq+0], F1 = f[4*jq+1], F2 = f[4*jq+2], F3 = f[4*jq+3];
                wait_vm0(F0, F1, F2, F3);   // first iter: real drain; rest: no-op
                int tries = 0;
                while (pois(F0) | pois(F1) | pois(F2) | pois(F3)) {
                    __builtin_amdgcn_s_sleep(1);
                    const unsigned short* rp = ap + jq * 128;
                    if (++tries <= 16) {
                        // fast path retry: XCD-local L2
                        F0 = ld16_sc0p(rp);       F1 = ld16_sc0p(rp + 32);
                        F2 = ld16_sc0p(rp + 64);  F3 = ld16_sc0p(rp + 96);
                        wait_vm0(F0, F1, F2, F3);
                    } else {
                        // escalation: agent scope = L3 truth (producer wrote
                        // through) -> correct under any WG->XCD placement
                        union { unsigned long long u[2]; i32x4 v; } t0, t1, t2, t3;
                        t0.u[0] = ld8(rp);      t0.u[1] = ld8(rp + 4);
                        t1.u[0] = ld8(rp + 32); t1.u[1] = ld8(rp + 36);
                        t2.u[0] = ld8(rp + 64); t2.u[1] = ld8(rp + 68);
                        t3.u[0] = ld8(rp + 96); t3.u[1] = ld8(rp + 100);
                        F0 = t0.v; F1 = t1.v; F2 = t2.v; F3 = t3.v;
                    }
                }
                union { i32x4 v; short8 s; } a0, a1, a2, a3;
                a0.v = F0; a1.v = F1; a2.v = F2; a3.v = F3;
                // z^T = Wh^T (A) · h^T (B): output col = batch, rows = h-cols
                acc0 = __builtin_amdgcn_mfma_f32_16x16x32_bf16(bfrag[4*jq+0], a0.s, acc0, 0, 0, 0);
                acc1 = __builtin_amdgcn_mfma_f32_16x16x32_bf16(bfrag[4*jq+1], a1.s, acc1, 0, 0, 0);
                acc2 = __builtin_amdgcn_mfma_f32_16x16x32_bf16(bfrag[4*jq+2], a2.s, acc2, 0, 0, 0);
                acc3 = __builtin_amdgcn_mfma_f32_16x16x32_bf16(bfrag[4*jq+3], a3.s, acc3, 0, 0, 0);
            }
        }
        // gate math: lane (m,q) produces h for batch b0+m, cols colbase+q*4+r
        u16x4 o;
#pragma unroll
        for (int r = 0; r < 4; ++r) {
            float z  = acc0[r] + acc1[r] + acc2[r] + acc3[r] + bf2f(xv[r]);
            float e  = __expf(-z);
            float sg = 1.f / (1.f + e);           // sigmoid(z)
            float gg = 2.f / (1.f + e * e) - 1.f; // tanh(z) via same exp
            c[r] = sg * (c[r] + gg);
            float ec = __expf(-2.f * c[r]);
            float th = 2.f / (1.f + ec) - 1.f;    // tanh(c)
            o[r] = f2bf(sg * th);
        }
        union { u16x4 v; unsigned long long u; } hu;
        hu.v = o;
        if (hu.u == POISON64) hu.u ^= 1ull;       // never store the sentinel
        // ONE atomic 8B agent store (write-through: local L2 + L3)
        st8(hs + ((size_t)l * B_ + b0 + m) * H_ + colbase + q * 4, hu.u);
    }
}

// ------------------------------------------------------------- k3: output
__global__ __launch_bounds__(256) void k3_out(
    const unsigned short* __restrict__ hs,
    const float* __restrict__ Wo, const float* __restrict__ bo,
    const int* __restrict__ slen, float* __restrict__ out)
{
    const int w    = threadIdx.x >> 6;
    const int lane = threadIdx.x & 63;
    const int r    = blockIdx.x * 4 + w;   // r = b*L + l
    const int b    = r >> 8;
    const int l    = r & 255;

    const unsigned short* hp = hs + ((size_t)l * B_ + b) * H_ + lane * 16;
    const float* wp = Wo + (size_t)lane * 32;
    float u0 = 0.f, u1 = 0.f;
#pragma unroll
    for (int j0 = 0; j0 < 16; j0 += 8) {
        short8 hv = *(const short8*)(hp + j0);
#pragma unroll
        for (int j = 0; j < 8; ++j) {
            float h = bf2f((unsigned short)hv[j]);
            f32x2 wv = *(const f32x2*)(wp + (j0 + j) * 2);
            u0 += h * wv[0];
            u1 += h * wv[1];
        }
    }
#pragma unroll
    for (int off = 32; off; off >>= 1) {
        u0 += __shfl_down(u0, off);
        u1 += __shfl_down(u1, off);
    }
    if (lane == 0) {
        float o0, o1;
        if (l <= slen[b]) {
            o0 = 1.f / (1.f + __expf(-(u0 + bo[0])));
            o1 = 1.f / (1.f + __expf(-(u1 + bo[1])));
        } else {
            o0 = 0.f; o1 = 1.f;
        }
        out[(size_t)r * 2]     = o0;
        out[(size_t)r * 2 + 1] = o1;
    }
}

// ----------------------------------------------------------------- launch
extern "C" void kernel_launch(void* const* d_in, const int* in_sizes, int n_in,
                              void* d_out, int out_size, void* d_ws, size_t ws_size,
                              hipStream_t stream)
{
    const float* x    = (const float*)d_in[0];
    const int*   slen = (const int*)d_in[1];
    const float* Wh   = (const float*)d_in[2];
    const float* bh   = (const float*)d_in[3];
    const float* Wx   = (const float*)d_in[4];
    const float* bx   = (const float*)d_in[5];
    const float* Wo   = (const float*)d_in[6];
    const float* bo   = (const float*)d_in[7];
    float* out = (float*)d_out;

    char* ws = (char*)d_ws;
    unsigned short* Whb_t = (unsigned short*)(ws);                     // 2 MiB
    unsigned short* Wxb_t = (unsigned short*)(ws + (2u << 20));        // 1 MiB
    float*          bxh   = (float*)(ws + (3u << 20));                 // 4 KiB
    unsigned short* xp    = (unsigned short*)(ws + (4u << 20));        // 64 MiB
    unsigned short* hs    = (unsigned short*)(ws + (68u << 20));       // 64 MiB

    k0_prep<<<512, 256, 0, stream>>>(Wh, Wx, bh, bx, Whb_t, Wxb_t, bxh, hs);
    k1_xproj<<<2048, 256, 0, stream>>>(x, Wxb_t, bxh, xp);
    k2_scan<<<256, 128, 0, stream>>>(Whb_t, xp, hs);
    k3_out<<<8192, 256, 0, stream>>>(hs, Wo, bo, slen, out);
}

// Round 5
// 1798.229 us; speedup vs baseline: 2.2849x; 2.2849x over previous
//
#include <hip/hip_runtime.h>

// RNNModule: LSTM-like scan with shared gate pre-activation.
// B=128, L=256, D=512, H=1024, O=2.
//
//  k0_prep : transpose+convert Wh/Wx to bf16 col-major, bxh=bx+bh,
//            poison-fill hs (0xAA sentinel for k2's dataflow).
//  k1_xproj: xp[l][b][n] = bf16( x[b,l,:]@Wx[:,n] + bx[n] + bh[n] )
//  k2_scan : 256 steps, pure dataflow (no inter-WG barrier). 8 groups
//            (16 batch rows) x 8 WGs (512 thr, 128 cols each; wave owns 16
//            cols, Wh slice register-resident). Each WG stages the group's
//            32 KB h-slice from L3 ONCE into LDS (sc0+sc1 loads, poison
//            poll), then 8 waves read B fragments from LDS. This cuts the
//            per-step cross-WG L3 broadcast 8x vs R2-R4 (the measured
//            bottleneck). R4 lesson: sc1 stores bypass the local L2, so
//            sc0-only polls see stale lines forever -> ALL exchange accesses
//            are sc0+sc1 (coherence point).
//  k3_out  : out[b*L+l] = mask ? sigmoid(hs[l][b]@Wo + bo) : (0,1)

#define B_ 128
#define L_ 256
#define D_ 512
#define H_ 1024

#define POISON64 0xAAAAAAAAAAAAAAAAull

typedef __attribute__((ext_vector_type(8))) short short8;
typedef __attribute__((ext_vector_type(4))) float f32x4;
typedef __attribute__((ext_vector_type(2))) float f32x2;
typedef __attribute__((ext_vector_type(4))) unsigned short u16x4;
typedef __attribute__((ext_vector_type(4))) int i32x4;

__device__ __forceinline__ unsigned short f2bf(float f) {
    unsigned int u = __float_as_uint(f);
    return (unsigned short)((u + 0x8000u) >> 16);  // round-half-up to bf16
}
__device__ __forceinline__ float bf2f(unsigned short s) {
    return __uint_as_float(((unsigned int)s) << 16);
}

// agent-scope 8B atomic store: write-through to the coherence point (L3)
__device__ __forceinline__ void st8(unsigned short* p, unsigned long long v) {
    __hip_atomic_store((unsigned long long*)p, v,
                       __ATOMIC_RELAXED, __HIP_MEMORY_SCOPE_AGENT);
}

// 16B load bypassing BOTH L1 (sc0) and the non-coherent XCD L2 (sc1):
// reads the coherence point. 8B halves arrive untorn (producer stores are
// 8B atomics; we validate each half against the sentinel separately).
template<int OFF>
__device__ __forceinline__ i32x4 ld16cc(const unsigned short* p) {
    i32x4 r;
    asm volatile("global_load_dwordx4 %0, %1, off offset:%2 sc0 sc1"
                 : "=v"(r) : "v"(p), "i"(OFF) : "memory");
    return r;
}
// drain vmcnt and pin the 4 tied values so no use is scheduled earlier
__device__ __forceinline__ void wait_vm0(i32x4& a, i32x4& b, i32x4& c, i32x4& d) {
    asm volatile("s_waitcnt vmcnt(0)" : "+v"(a), "+v"(b), "+v"(c), "+v"(d));
}
__device__ __forceinline__ bool pois(const i32x4 v) {
    bool h0 = (v.x == (int)0xAAAAAAAAu) && (v.y == (int)0xAAAAAAAAu);
    bool h1 = (v.z == (int)0xAAAAAAAAu) && (v.w == (int)0xAAAAAAAAu);
    return h0 | h1;
}

// ---------------------------------------------------------------- k0: prep
__global__ __launch_bounds__(256) void k0_prep(
    const float* __restrict__ Wh, const float* __restrict__ Wx,
    const float* __restrict__ bh, const float* __restrict__ bx,
    unsigned short* __restrict__ Whb_t, unsigned short* __restrict__ Wxb_t,
    float* __restrict__ bxh, unsigned short* __restrict__ hs)
{
    const int stride = gridDim.x * blockDim.x;
    const int t0 = blockIdx.x * blockDim.x + threadIdx.x;
    for (int i = t0; i < H_ * H_; i += stride) {
        int n = i >> 10, k = i & 1023;
        Whb_t[i] = f2bf(Wh[k * H_ + n]);
    }
    for (int i = t0; i < H_ * D_; i += stride) {
        int n = i >> 9, k = i & 511;
        Wxb_t[i] = f2bf(Wx[k * H_ + n]);
    }
    for (int i = t0; i < H_; i += stride) bxh[i] = bx[i] + bh[i];
    // poison-fill hs: k2's sentinel must not depend on harness pre-state
    unsigned long long* hp = (unsigned long long*)hs;
    const int nq = (L_ * B_ * H_) / 4;
    for (int i = t0; i < nq; i += stride) hp[i] = POISON64;
}

// ------------------------------------------------------------ k1: x @ Wx
// Operand-swapped MFMA (A=Wx^T frag, B=x frag): D[row=outcol][col=batch],
// so each lane's 4 results are 4 consecutive n -> 8B store into xp[l][b][n].
__global__ __launch_bounds__(256) void k1_xproj(
    const float* __restrict__ x, const unsigned short* __restrict__ Wxb_t,
    const float* __restrict__ bxh, unsigned short* __restrict__ xp)
{
    const int nt   = blockIdx.x & 3;
    const int mt   = blockIdx.x >> 2;
    const int w    = threadIdx.x >> 6;
    const int lane = threadIdx.x & 63;
    const int m    = lane & 15, q = lane >> 4;
    const int m0   = mt * 64;
    const int l    = m0 >> 7;
    const int brow = (m0 & 127) + w * 16;
    const int n0   = nt * 256;

    const float* ap = x + ((size_t)(brow + m) * L_ + l) * D_ + q * 8;

    f32x4 acc[16];
#pragma unroll
    for (int t = 0; t < 16; ++t) acc[t] = (f32x4){0.f, 0.f, 0.f, 0.f};

#pragma unroll 4
    for (int kk = 0; kk < 16; ++kk) {
        f32x4 av0 = *(const f32x4*)(ap + kk * 32);
        f32x4 av1 = *(const f32x4*)(ap + kk * 32 + 4);
        short8 a8;
        a8[0] = (short)f2bf(av0[0]); a8[1] = (short)f2bf(av0[1]);
        a8[2] = (short)f2bf(av0[2]); a8[3] = (short)f2bf(av0[3]);
        a8[4] = (short)f2bf(av1[0]); a8[5] = (short)f2bf(av1[1]);
        a8[6] = (short)f2bf(av1[2]); a8[7] = (short)f2bf(av1[3]);
#pragma unroll
        for (int t = 0; t < 16; ++t) {
            short8 b8 = *(const short8*)(Wxb_t +
                        (size_t)(n0 + t * 16 + m) * D_ + kk * 32 + q * 8);
            acc[t] = __builtin_amdgcn_mfma_f32_16x16x32_bf16(b8, a8, acc[t], 0, 0, 0);
        }
    }

#pragma unroll
    for (int t = 0; t < 16; ++t) {
        const int c0 = n0 + t * 16 + q * 4;       // 4 consecutive out-cols
        f32x4 bias = *(const f32x4*)(bxh + c0);
        u16x4 o;
#pragma unroll
        for (int r = 0; r < 4; ++r) o[r] = f2bf(acc[t][r] + bias[r]);
        *(u16x4*)(xp + ((size_t)l * B_ + brow + m) * H_ + c0) = o;
    }
}

// ------------------------------------------------------------- k2: scan
// Grid: 64 WGs x 512 thr. group g=blk&7 (batch rows g*16..+15), wg=blk>>3
// (cols wg*128..+127; wave w owns 16). LDS-staged broadcast, double-buffered,
// ONE __syncthreads per step (race-free: barrier(l) orders stage(l+1) writes
// of buf[(l+1)&1] after all compute(l-1) reads of that same buffer).
__global__ __launch_bounds__(512, 2) void k2_scan(
    const unsigned short* __restrict__ Whb_t,
    const unsigned short* __restrict__ xp,
    unsigned short* __restrict__ hs)
{
    // rows padded to 1032 shorts (2064 B): LDS bank advance 4/row -> only
    // free 2-way conflicts on the 16-row fragment reads.
    __shared__ unsigned short buf[2][16][1032];

    const int g    = blockIdx.x & 7;
    const int wg   = blockIdx.x >> 3;
    const int tid  = threadIdx.x;
    const int w    = tid >> 6;
    const int lane = tid & 63;
    const int mb   = lane & 15, q = lane >> 4;
    const int b0   = g * 16;
    const int colw = wg * 128 + w * 16;

    // persistent A fragments: Wh^T[colw+mb][k], k = kk*32 + q*8 + j
    short8 afrag[32];
    {
        const unsigned short* wp = Whb_t + (size_t)(colw + mb) * H_ + q * 8;
#pragma unroll
        for (int kk = 0; kk < 32; ++kk)
            afrag[kk] = *(const short8*)(wp + kk * 32);
    }

    // staging mapping: thread handles row srow, 16B-chunks scid+32i (i<4)
    const int srow = tid >> 5;   // 0..15
    const int scid = tid & 31;   // 0..31

    float c[4] = {0.f, 0.f, 0.f, 0.f};

    for (int l = 0; l < L_; ++l) {
        unsigned short* lbuf = &buf[l & 1][0][0];
        if (l > 0) {
            // ---- stage h[l-1] (16 x 1024, 32 KB) from L3 into LDS, once
            const unsigned short* gp =
                hs + ((size_t)(l - 1) * B_ + b0 + srow) * H_ + scid * 8;
            i32x4 v0, v1, v2, v3;
            for (;;) {
                v0 = ld16cc<0>(gp);    v1 = ld16cc<512>(gp);
                v2 = ld16cc<1024>(gp); v3 = ld16cc<1536>(gp);
                wait_vm0(v0, v1, v2, v3);
                if (!(pois(v0) | pois(v1) | pois(v2) | pois(v3))) break;
                __builtin_amdgcn_s_sleep(1);
            }
            unsigned short* lp = lbuf + srow * 1032 + scid * 8;
            *(i32x4*)(lp)       = v0;
            *(i32x4*)(lp + 256) = v1;
            *(i32x4*)(lp + 512) = v2;
            *(i32x4*)(lp + 768) = v3;
        }
        __syncthreads();

        f32x4 acc0 = {0.f,0.f,0.f,0.f}, acc1 = {0.f,0.f,0.f,0.f};
        f32x4 acc2 = {0.f,0.f,0.f,0.f}, acc3 = {0.f,0.f,0.f,0.f};
        if (l > 0) {
            // B fragments from LDS: lane (mb,q) reads h[mb][kb*32+q*8 ..+7]
            const unsigned short* rp = lbuf + mb * 1032 + q * 8;
#pragma unroll
            for (int kb = 0; kb < 32; kb += 4) {
                short8 bb0 = *(const short8*)(rp + (kb + 0) * 32);
                short8 bb1 = *(const short8*)(rp + (kb + 1) * 32);
                short8 bb2 = *(const short8*)(rp + (kb + 2) * 32);
                short8 bb3 = *(const short8*)(rp + (kb + 3) * 32);
                acc0 = __builtin_amdgcn_mfma_f32_16x16x32_bf16(afrag[kb + 0], bb0, acc0, 0, 0, 0);
                acc1 = __builtin_amdgcn_mfma_f32_16x16x32_bf16(afrag[kb + 1], bb1, acc1, 0, 0, 0);
                acc2 = __builtin_amdgcn_mfma_f32_16x16x32_bf16(afrag[kb + 2], bb2, acc2, 0, 0, 0);
                acc3 = __builtin_amdgcn_mfma_f32_16x16x32_bf16(afrag[kb + 3], bb3, acc3, 0, 0, 0);
            }
        }
        // gate math: lane (mb,q) produces h for batch b0+mb, cols colw+q*4+r
        u16x4 xv = *(const u16x4*)(xp + ((size_t)l * B_ + b0 + mb) * H_ + colw + q * 4);
        u16x4 o;
#pragma unroll
        for (int r = 0; r < 4; ++r) {
            float z  = acc0[r] + acc1[r] + acc2[r] + acc3[r] + bf2f(xv[r]);
            float e  = __expf(-z);
            float sg = 1.f / (1.f + e);           // sigmoid(z)
            float gg = 2.f / (1.f + e * e) - 1.f; // tanh(z) via same exp
            c[r] = sg * (c[r] + gg);
            float ec = __expf(-2.f * c[r]);
            float th = 2.f / (1.f + ec) - 1.f;    // tanh(c)
            o[r] = f2bf(sg * th);
        }
        union { u16x4 v; unsigned long long u; } hu;
        hu.v = o;
        if (hu.u == POISON64) hu.u ^= 1ull;       // never store the sentinel
        st8(hs + ((size_t)l * B_ + b0 + mb) * H_ + colw + q * 4, hu.u);
    }
}

// ------------------------------------------------------------- k3: output
__global__ __launch_bounds__(256) void k3_out(
    const unsigned short* __restrict__ hs,
    const float* __restrict__ Wo, const float* __restrict__ bo,
    const int* __restrict__ slen, float* __restrict__ out)
{
    const int w    = threadIdx.x >> 6;
    const int lane = threadIdx.x & 63;
    const int r    = blockIdx.x * 4 + w;   // r = b*L + l
    const int b    = r >> 8;
    const int l    = r & 255;

    const unsigned short* hp = hs + ((size_t)l * B_ + b) * H_ + lane * 16;
    const float* wp = Wo + (size_t)lane * 32;
    float u0 = 0.f, u1 = 0.f;
#pragma unroll
    for (int j0 = 0; j0 < 16; j0 += 8) {
        short8 hv = *(const short8*)(hp + j0);
#pragma unroll
        for (int j = 0; j < 8; ++j) {
            float h = bf2f((unsigned short)hv[j]);
            f32x2 wv = *(const f32x2*)(wp + (j0 + j) * 2);
            u0 += h * wv[0];
            u1 += h * wv[1];
        }
    }
#pragma unroll
    for (int off = 32; off; off >>= 1) {
        u0 += __shfl_down(u0, off);
        u1 += __shfl_down(u1, off);
    }
    if (lane == 0) {
        float o0, o1;
        if (l <= slen[b]) {
            o0 = 1.f / (1.f + __expf(-(u0 + bo[0])));
            o1 = 1.f / (1.f + __expf(-(u1 + bo[1])));
        } else {
            o0 = 0.f; o1 = 1.f;
        }
        out[(size_t)r * 2]     = o0;
        out[(size_t)r * 2 + 1] = o1;
    }
}

// ----------------------------------------------------------------- launch
extern "C" void kernel_launch(void* const* d_in, const int* in_sizes, int n_in,
                              void* d_out, int out_size, void* d_ws, size_t ws_size,
                              hipStream_t stream)
{
    const float* x    = (const float*)d_in[0];
    const int*   slen = (const int*)d_in[1];
    const float* Wh   = (const float*)d_in[2];
    const float* bh   = (const float*)d_in[3];
    const float* Wx   = (const float*)d_in[4];
    const float* bx   = (const float*)d_in[5];
    const float* Wo   = (const float*)d_in[6];
    const float* bo   = (const float*)d_in[7];
    float* out = (float*)d_out;

    char* ws = (char*)d_ws;
    unsigned short* Whb_t = (unsigned short*)(ws);                     // 2 MiB
    unsigned short* Wxb_t = (unsigned short*)(ws + (2u << 20));        // 1 MiB
    float*          bxh   = (float*)(ws + (3u << 20));                 // 4 KiB
    unsigned short* xp    = (unsigned short*)(ws + (4u << 20));        // 64 MiB
    unsigned short* hs    = (unsigned short*)(ws + (68u << 20));       // 64 MiB

    k0_prep<<<512, 256, 0, stream>>>(Wh, Wx, bh, bx, Whb_t, Wxb_t, bxh, hs);
    k1_xproj<<<2048, 256, 0, stream>>>(x, Wxb_t, bxh, xp);
    k2_scan<<<64, 512, 0, stream>>>(Whb_t, xp, hs);
    k3_out<<<8192, 256, 0, stream>>>(hs, Wo, bo, slen, out);
}